// Round 4
// baseline (214.325 us; speedup 1.0000x reference)
//
#include <hip/hip_runtime.h>

// Conv2d 3x3 s1 p1 as implicit GEMM, bf16 MFMA, fp32 accumulate.
// N=32, Cin=128, H=W=56, Cout=256. M=100352, K=1152 (kh,kw outer / ci inner).
// R6: LDS-traffic-optimized geometry. Block 256m x 128co, 4 waves, per-wave
//     128x64 (acc=128 AGPR -> granted 256 regs/wave -> 8 waves/CU = 2 blocks).
//     Single 48 KB LDS buffer, 2-sync/K-tile (m97 skeleton, m114 inter-block
//     overlap). LDS read/MFMA drops 512B -> 384B. Padded-NHWC xt, f32x4
//     epilogue, pair-preserving XCD chunk swizzle (784 = 8*98).

#define NB   32
#define CIN  128
#define HH   56
#define WWD  56
#define COUT 256
#define HWP  3136      // 56*56
#define KTOT 1152      // 9*128
#define HP   58        // padded spatial dim
#define XTN  (HP*HP*CIN)   // 430592 elems per image

typedef __bf16 bf16x8 __attribute__((ext_vector_type(8)));
typedef float  f32x4  __attribute__((ext_vector_type(4)));
typedef unsigned short u16;
typedef u16 u16x4 __attribute__((ext_vector_type(4)));
typedef u16 u16x8 __attribute__((ext_vector_type(8)));

__device__ __forceinline__ u16 f2b(float f) {
  unsigned u = __float_as_uint(f);
  u += 0x7fffu + ((u >> 16) & 1u);
  return (u16)(u >> 16);
}

__device__ __forceinline__ void load_lds16(const u16* g, u16* l) {
  __builtin_amdgcn_global_load_lds(
      (const __attribute__((address_space(1))) unsigned int*)g,
      (__attribute__((address_space(3))) unsigned int*)l, 16, 0, 0);
}

// x: [32][128][3136] f32 -> xt: [32][58][58][128] bf16 (NCHW -> padded NHWC + cvt)
// Interior only; border zeroed by k_transform_w.
__global__ __launch_bounds__(256) void k_transpose_x(const float* __restrict__ x,
                                                     u16* __restrict__ xt) {
  __shared__ u16 tile[64][68];   // row = c; 136B row stride
  const int n  = blockIdx.z;
  const int p0 = blockIdx.x * 64;
  const int c0 = blockIdx.y * 64;
  const int t  = threadIdx.x;

  const float* xp = x + (size_t)n * CIN * HWP + (size_t)c0 * HWP + p0;
  const int pl = (t & 15) * 4;   // pixel offset within tile
  const int cr = t >> 4;         // channel row 0..15 (+16j)
#pragma unroll
  for (int j = 0; j < 4; ++j) {
    int c = cr + j * 16;
    f32x4 v = *(const f32x4*)&xp[(size_t)c * HWP + pl];
    u16x4 h;
    h[0] = f2b(v[0]); h[1] = f2b(v[1]); h[2] = f2b(v[2]); h[3] = f2b(v[3]);
    *(u16x4*)&tile[c][pl] = h;
  }
  __syncthreads();
  u16* xb = xt + (size_t)n * XTN + c0;
  const int ch = (t & 7) * 8;    // channel chunk
  const int pr = t >> 3;         // pixel row 0..31 (+32j)
#pragma unroll
  for (int j = 0; j < 2; ++j) {
    int p  = pr + j * 32;
    int s  = p0 + p;
    int oh = s / WWD;
    int ow = s - oh * WWD;
    u16x8 o;
#pragma unroll
    for (int i = 0; i < 8; ++i) o[i] = tile[ch + i][p];
    *(u16x8*)&xb[((size_t)(oh + 1) * HP + (ow + 1)) * CIN + ch] = o;
  }
}

// w: [256][128][3][3] f32 -> Wt: [256][1152] bf16 with k = (kh*3+kw)*128 + ci
// Also zeroes the xt border (32 * 228 pixels * 128 ch = 933888 elems).
__global__ __launch_bounds__(256) void k_transform_w(const float* __restrict__ w,
                                                     u16* __restrict__ Wt,
                                                     u16* __restrict__ xt) {
  int o = blockIdx.x * 256 + threadIdx.x;
  if (o < COUT * KTOT) {
    int co  = o / KTOT;
    int rem = o - co * KTOT;
    int kk  = rem >> 7;      // (kh*3+kw)
    int ci  = rem & 127;
    int kh  = kk / 3;
    int kw  = kk - kh * 3;
    Wt[o] = f2b(w[(((size_t)co * CIN + ci) * 3 + kh) * 3 + kw]);
  }
#pragma unroll
  for (int j = 0; j < 4; ++j) {
    unsigned e = (unsigned)o + j * 294912u;
    if (e < 933888u) {
      unsigned n  = e / 29184u;         // 228*128
      unsigned rm = e - n * 29184u;
      unsigned bp = rm >> 7;            // border pixel 0..227
      unsigned ch = rm & 127u;
      unsigned ih, iw;
      if (bp < 58u)       { ih = 0;  iw = bp; }
      else if (bp < 116u) { ih = 57; iw = bp - 58u; }
      else { unsigned c2 = bp - 116u; ih = 1u + (c2 >> 1); iw = (c2 & 1u) ? 57u : 0u; }
      xt[(((size_t)n * HP + ih) * HP + iw) * CIN + ch] = (u16)0;
    }
  }
}

// ---- GEMM: grid 784 (392 m-tiles x 2 co-tiles), block 256 (4 waves, 2m x 2co).
// 256x128 tile, BK=64, 18 K-tiles. Single 48 KB LDS buffer; per K-tile:
// sync (readers done) -> stage 48 KB via global_load_lds -> sync -> MFMA.
// 2 blocks/CU: the co-resident block's MFMA hides this block's stage drain.

__device__ __forceinline__ int uX_off(int kt) {
  int ksp = kt >> 1;
  int kh  = (ksp >= 6) ? 2 : ((ksp >= 3) ? 1 : 0);
  int kw  = ksp - kh * 3;
  return (kh * HP + kw) * CIN + ((kt & 1) << 6);
}

__global__ __launch_bounds__(256, 2) void k_conv_gemm(
    const u16* __restrict__ xt, const u16* __restrict__ Wt,
    const float* __restrict__ bias, float* __restrict__ out) {
  __shared__ u16 lX[16384];  // 256 rows x 64 k, 16B pieces XOR-swizzled (32 KB)
  __shared__ u16 lW[8192];   // 128 rows x 64 k (16 KB)

  const int tid  = threadIdx.x;
  const int wave = tid >> 6;
  const int lane = tid & 63;

  // XCD chunk swizzle (784 = 8*98 exact, bijective). Decode keeps the two
  // co-tiles of one m-tile (by=0,1) adjacent -> same XCD -> shared X panel in L2.
  const int bid  = blockIdx.x;
  const int orig = (bid & 7) * 98 + (bid >> 3);
  const int bx   = orig >> 1;
  const int by   = orig & 1;
  const int m0   = bx * 256;
  const int co0  = by * 128;

  const int r  = lane & 15;
  const int q  = lane >> 4;
  const int r7 = r & 7;
  const int wm = (wave & 1) * 128;   // m offset of this wave's 128x64
  const int wc = (wave >> 1) * 64;   // co offset

  // staging lane map: 8 rows x 8 swizzled 16B pieces per instruction
  const int rsub = lane >> 3;
  const int pso  = ((lane & 7) ^ rsub) * 8;

  int pbX[8], ldoA[8];
#pragma unroll
  for (int c = 0; c < 8; ++c) {
    const int rowb = wave * 64 + c * 8;
    const int m  = m0 + rowb + rsub;
    const int n  = m / HWP;
    const int s  = m - n * HWP;
    const int oh = s / WWD;
    const int ow = s - oh * WWD;
    pbX[c]  = ((n * HP + oh) * HP + ow) * CIN + pso;
    ldoA[c] = rowb * 64;
  }
  int pbW[4], ldoB[4];
#pragma unroll
  for (int c = 0; c < 4; ++c) {
    const int rowb = wave * 32 + c * 8;
    pbW[c]  = (co0 + rowb + rsub) * KTOT + pso;
    ldoB[c] = rowb * 64;
  }
  float bias_r[4];
#pragma unroll
  for (int tj = 0; tj < 4; ++tj) bias_r[tj] = bias[co0 + wc + tj * 16 + r];

  f32x4 acc[8][4];
#pragma unroll
  for (int i = 0; i < 8; ++i)
#pragma unroll
    for (int j = 0; j < 4; ++j) acc[i][j] = (f32x4){0.f, 0.f, 0.f, 0.f};

#pragma unroll 1
  for (int kt = 0; kt < 18; ++kt) {
    const int uxo = uX_off(kt);
    const int uwo = kt * 64;
    __syncthreads();   // all waves done reading LDS from previous K-tile
#pragma unroll
    for (int c = 0; c < 8; ++c)
      load_lds16(xt + pbX[c] + uxo, &lX[ldoA[c]]);
#pragma unroll
    for (int c = 0; c < 4; ++c)
      load_lds16(Wt + pbW[c] + uwo, &lW[ldoB[c]]);
    __syncthreads();   // drains vmcnt -> staged data visible

#pragma unroll
    for (int kk = 0; kk < 2; ++kk) {
      const int sw = ((kk * 4 + q) ^ r7) * 8;   // swizzled segment offset (elems)
      bf16x8 b[4];
#pragma unroll
      for (int tj = 0; tj < 4; ++tj)
        b[tj] = *(const bf16x8*)&lW[(wc + tj * 16 + r) * 64 + sw];
      bf16x8 a[8];
#pragma unroll
      for (int ti = 0; ti < 8; ++ti)
        a[ti] = *(const bf16x8*)&lX[(wm + ti * 16 + r) * 64 + sw];
#pragma unroll
      for (int ti = 0; ti < 8; ++ti)
#pragma unroll
        for (int tj = 0; tj < 4; ++tj)
          acc[ti][tj] = __builtin_amdgcn_mfma_f32_16x16x32_bf16(
              a[ti], b[tj], acc[ti][tj], 0, 0, 0);
    }
  }

  // Epilogue: mfma(a=X, b=W) -> col(lane&15)=co, row(q*4+e)=m.
  // f32x4 store along s (m4 is 4-aligned, never crosses a 3136-row).
#pragma unroll
  for (int ti = 0; ti < 8; ++ti) {
    const int m4 = m0 + wm + ti * 16 + q * 4;
    const int n  = m4 / HWP;
    const int s  = m4 - n * HWP;
    float* op = out + (size_t)n * COUT * HWP + s;
#pragma unroll
    for (int tj = 0; tj < 4; ++tj) {
      const int co = co0 + wc + tj * 16 + r;
      f32x4 v = acc[ti][tj];
      const float bv = bias_r[tj];
      v[0] += bv; v[1] += bv; v[2] += bv; v[3] += bv;
      *(f32x4*)(op + (size_t)co * HWP) = v;
    }
  }
}

extern "C" void kernel_launch(void* const* d_in, const int* in_sizes, int n_in,
                              void* d_out, int out_size, void* d_ws, size_t ws_size,
                              hipStream_t stream) {
  const float* x    = (const float*)d_in[0];
  const float* w    = (const float*)d_in[1];
  const float* bias = (const float*)d_in[2];
  float* out        = (float*)d_out;

  u16* xt = (u16*)d_ws;                       // 13,778,944 bf16 = 27.6 MB (padded NHWC)
  u16* Wt = xt + (size_t)NB * XTN;            // 294,912 bf16

  k_transform_w<<<dim3(1152), dim3(256), 0, stream>>>(w, Wt, xt);
  k_transpose_x<<<dim3(49, 2, 32), dim3(256), 0, stream>>>(x, xt);
  k_conv_gemm<<<dim3(784), dim3(256), 0, stream>>>(xt, Wt, bias, out);
}